// Round 5
// baseline (149.310 us; speedup 1.0000x reference)
//
#include <hip/hip_runtime.h>
#include <cstdint>
#include <cstddef>

// MMD loss, N=8192 (b=4096), D=512.
//   bw closed form: sum(L2) = 2n*S - 2*||colsum||^2
//   R8: 5 kernels -> 3. Profile showed every kernel < 44 us while wall time
//       = 109 us: ~50 us lives in 4 inter-kernel dependency hops (~10-12 us
//       each). Fuse via fence+ticket (last-arriving block does the serial
//       tail; no spin-wait, no co-residency requirement):
//         K1 rowstats (also re-zeros ticket counters -> graph-replay safe)
//         K2 colsum+bw  (ticket tail: 288KB reduce -> c16)
//         K3 mmd+final  (ticket tail: 2080-float reduce -> out)
//       Cross-XCD safety: release = __syncthreads (drains stores) +
//       __threadfence before atomicAdd; acquire = __threadfence after
//       winning ticket (invalidates stale L1/L2 lines from prior replay).
//       + dtile-split epilogue: only the 64 diagonal blocks pay the
//       per-element rl==cl compare/select.
//   R7: LDS-staged double-buffered k_mmd (global_load_lds width=16),
//       XCD-aware block swizzle (2080 = 8*260, bijective). Neutral vs R6
//       (-2us): operand delivery was not the bottleneck. Kept (it halves L2
//       traffic; harmless).
//   R6: FRAGMENT-MAJOR int8 layout: chunk (rb,c) [16 rows x 16B] contiguous
//       256B; a wave's fragment load = one coalesced 1KB transaction.
//   R4: INT8 MFMA 16x16x64 (scale 1/16, exact int32 acc), diag forced exact.
//   Epilogue: sum_k exp(-L2/(bw*2^k)) = e+e^2+e^4+e^8+e^16, e=exp2(-L2*log2e/(16bw))
//   R2: no single-address atomics in the hot path (were 107us of serialization).

#define D_DIM 512
#define B_ROWS 4096
#define N_ROWS 8192
#define NTILES 64        // 8192 / 128
#define NBLK_MMD 2080    // 64*65/2
#define LDS_HALF 8192    // A (or B) panel slice per K-step: 8 rb x 1KB
#define LDS_BUF 16384    // A + B per K-step

typedef __attribute__((ext_vector_type(4))) int i32x4;

__device__ inline float waveReduce(float v) {
    #pragma unroll
    for (int off = 32; off > 0; off >>= 1) v += __shfl_down(v, off, 64);
    return v;
}

__device__ inline int q8(float x) {
    int v = (int)rintf(x * 16.f);             // RNE; s = 1/16
    v = v > 127 ? 127 : v;
    v = v < -127 ? -127 : v;
    return v & 255;
}

// Fragment-major address: row r, 16B-chunk c (0..31):
//   rb = r>>4, w = r&15;  byte addr = ((rb*32 + c) << 8) + w*16

// ---- K1: per-row sq norms (fp32, exact) + fp32->int8 quantize (frag-major) ----
__global__ __launch_bounds__(256) void k_rowstats(const float* __restrict__ src,
                                                  const float* __restrict__ tgt,
                                                  unsigned char* __restrict__ Tp,
                                                  float* __restrict__ sq,
                                                  unsigned int* __restrict__ cnt) {
    if (blockIdx.x == 0 && threadIdx.x == 0) {
        cnt[0] = 0u;                         // K2 ticket
        cnt[1] = 0u;                         // K3 ticket
    }                                        // visible at kernel-end release
    int wave = threadIdx.x >> 6;
    int lane = threadIdx.x & 63;
    int row  = blockIdx.x * 4 + wave;
    const float* base = (row < B_ROWS) ? (src + (size_t)row * D_DIM)
                                       : (tgt + (size_t)(row - B_ROWS) * D_DIM);
    float4 a = ((const float4*)base)[lane * 2];
    float4 b = ((const float4*)base)[lane * 2 + 1];
    uint2 o;   // bytes [8*lane, 8*lane+8) of the quantized row
    o.x = (unsigned)(q8(a.x) | (q8(a.y) << 8) | (q8(a.z) << 16) | (q8(a.w) << 24));
    o.y = (unsigned)(q8(b.x) | (q8(b.y) << 8) | (q8(b.z) << 16) | (q8(b.w) << 24));
    int rb = row >> 4, w = row & 15;
    int c  = lane >> 1, h = lane & 1;
    *(uint2*)(Tp + (((size_t)(rb * 32 + c)) << 8) + w * 16 + h * 8) = o;
    float s = a.x*a.x + a.y*a.y + a.z*a.z + a.w*a.w
            + b.x*b.x + b.y*b.y + b.z*b.z + b.w*b.w;
    s = waveReduce(s);
    if (lane == 0) sq[row] = s;
}

// ---- K2: int8 column-sum partials + (ticket tail) bandwidth -> c16 ----
__global__ __launch_bounds__(256) void k_colbw(const unsigned int* __restrict__ Tu,
                                               const float* __restrict__ sq,
                                               int* __restrict__ partial,
                                               float* __restrict__ c16out,
                                               unsigned int* __restrict__ cnt) {
    int t   = threadIdx.x;
    int u   = t & 127;
    int c   = u >> 2, q = u & 3;
    int sub = t >> 7;              // w in [sub*8, sub*8+8)
    int a0 = 0, a1 = 0, a2 = 0, a3 = 0;
    #pragma unroll 2
    for (int j = 0; j < 8; ++j) {
        int rb = blockIdx.x * 8 + j;
        #pragma unroll
        for (int wv = 0; wv < 8; ++wv) {
            int w = sub * 8 + wv;
            unsigned int v = Tu[(size_t)(rb * 32 + c) * 64 + w * 4 + q];
            a0 += (int)(signed char)(v);
            a1 += (int)(signed char)(v >> 8);
            a2 += (int)(signed char)(v >> 16);
            a3 += (int)(signed char)(v >> 24);
        }
    }
    int basep = (blockIdx.x * 2 + sub) * 512 + u * 4;
    partial[basep + 0] = a0;
    partial[basep + 1] = a1;
    partial[basep + 2] = a2;
    partial[basep + 3] = a3;

    // ---- ticket: last-arriving block computes c16 ----
    __shared__ bool isLast;
    __syncthreads();                         // all stores vmcnt-drained
    if (t == 0) {
        __threadfence();                     // release to device scope
        isLast = (atomicAdd(cnt, 1u) == 63u);
    }
    __syncthreads();
    if (!isLast) return;
    __threadfence();                         // acquire: invalidate stale lines

    float p = 0.f;
    #pragma unroll
    for (int cc = 0; cc < 2; ++cc) {
        int col = t + cc * 256;
        int csum = 0;
        #pragma unroll 8
        for (int i = 0; i < 128; ++i) csum += partial[i * 512 + col];
        float cs = (float)csum * 0.0625f;    // * s (1/16)
        p += cs * cs;
    }
    float ssq = 0.f;
    #pragma unroll 8
    for (int i = 0; i < 32; ++i) ssq += sq[t + i * 256];
    __shared__ float r4[4], q4[4];
    float wp = waveReduce(p);
    float wq = waveReduce(ssq);
    if ((t & 63) == 0) { r4[t >> 6] = wp; q4[t >> 6] = wq; }
    __syncthreads();
    if (t == 0) {
        double P = 0.0, Q = 0.0;
        #pragma unroll
        for (int i = 0; i < 4; ++i) { P += r4[i]; Q += q4[i]; }
        double n = (double)N_ROWS;
        double sumL2 = 2.0 * n * Q - 2.0 * P;
        double bw = sumL2 / (n * n - n) / 4.0;   // / KERNEL_MUL^(NUM/2)
        c16out[0] = (float)(-1.4426950408889634 / (16.0 * bw));
    }
}

// ---- K3: LDS-staged int8 Gram + fused MMD epilogue + (ticket tail) final ----
__global__ __launch_bounds__(256) void k_mmd(const unsigned char* __restrict__ Tp,
                                             const float* __restrict__ sq,
                                             const float* __restrict__ c16in,
                                             float* __restrict__ blockpart,
                                             float* __restrict__ out,
                                             unsigned int* __restrict__ cnt) {
    // XCD swizzle: 2080 = 8 * 260 exactly -> bijective chunked remap.
    int hwbid = (int)blockIdx.x;
    int bid = (hwbid & 7) * 260 + (hwbid >> 3);

    int rem = bid;
    int ti = 0, rowlen = NTILES;
    while (rem >= rowlen) { rem -= rowlen; rowlen--; ti++; }
    int tj = ti + rem;

    int tid  = threadIdx.x;
    int wave = tid >> 6;
    int lane = tid & 63;
    int waveM = (wave >> 1) * 64;
    int waveN = (wave & 1) * 64;
    int l15   = lane & 15;
    int quad  = lane >> 4;

    float c16 = c16in[0];                    // -log2e/(16 bw)
    float cgq = -2.f * c16 * (1.f / 256.f);  // fold s^2 = 1/256

    int rbA0 = ti * 8;                       // panel bases (rb units)
    int rbB0 = tj * 8;

    __shared__ unsigned char lds[2 * LDS_BUF];   // 32 KB, double-buffered

    i32x4 acc[4][4];
    #pragma unroll
    for (int mi = 0; mi < 4; ++mi)
        #pragma unroll
        for (int ni = 0; ni < 4; ++ni)
            acc[mi][ni] = (i32x4){0, 0, 0, 0};

    // Stage K-step kk into buffer buf. Each wave: 4 x global_load_lds of
    // 1KB (lanes linear, 16B each). Wave w covers rb_local {2w, 2w+1} of
    // both panels. LDS layout = frag-major 1KB per rb_local, A then B.
    auto stage = [&](int buf, int kk) {
        unsigned char* lbase = lds + buf * LDS_BUF;
        #pragma unroll
        for (int s = 0; s < 2; ++s) {
            int rbl = wave * 2 + s;
            const unsigned char* gA =
                Tp + (((size_t)((rbA0 + rbl) * 32 + kk * 4)) << 8) + lane * 16;
            const unsigned char* gB =
                Tp + (((size_t)((rbB0 + rbl) * 32 + kk * 4)) << 8) + lane * 16;
            __builtin_amdgcn_global_load_lds(
                (const __attribute__((address_space(1))) void*)gA,
                (__attribute__((address_space(3))) void*)(lbase + rbl * 1024 + lane * 16),
                16, 0, 0);
            __builtin_amdgcn_global_load_lds(
                (const __attribute__((address_space(1))) void*)gB,
                (__attribute__((address_space(3))) void*)(lbase + LDS_HALF + rbl * 1024 + lane * 16),
                16, 0, 0);
        }
    };

    stage(0, 0);
    __syncthreads();                         // drains vmcnt(0) + barrier

    int aoff = ((wave >> 1) * 4) * 1024 + quad * 256 + l15 * 16;
    int boff = ((wave & 1) * 4) * 1024 + quad * 256 + l15 * 16;

    int buf = 0;
    for (int kk = 0; kk < 8; ++kk) {
        if (kk < 7) stage(buf ^ 1, kk + 1);  // prefetch next K-step

        const unsigned char* bufA = lds + buf * LDS_BUF;
        const unsigned char* bufB = bufA + LDS_HALF;
        i32x4 af[4], bf[4];
        #pragma unroll
        for (int mi = 0; mi < 4; ++mi)
            af[mi] = *(const i32x4*)(bufA + aoff + mi * 1024);
        #pragma unroll
        for (int ni = 0; ni < 4; ++ni)
            bf[ni] = *(const i32x4*)(bufB + boff + ni * 1024);
        #pragma unroll
        for (int mi = 0; mi < 4; ++mi)
            #pragma unroll
            for (int ni = 0; ni < 4; ++ni)
                acc[mi][ni] = __builtin_amdgcn_mfma_i32_16x16x64_i8(
                    af[mi], bf[ni], acc[mi][ni], 0, 0, 0);

        __syncthreads();                     // staged data ready; buf reusable
        buf ^= 1;
    }

    // epilogue: sq loads direct from global (tiny, L2-hot), pre-scaled
    const float* sqA = sq + ti * 128;
    const float* sqB = sq + tj * 128;
    float trow16[16];
    #pragma unroll
    for (int mi = 0; mi < 4; ++mi)
        #pragma unroll
        for (int r = 0; r < 4; ++r)
            trow16[mi * 4 + r] = sqA[waveM + mi * 16 + quad * 4 + r] * c16;
    float tcol16[4];
    #pragma unroll
    for (int ni = 0; ni < 4; ++ni)
        tcol16[ni] = sqB[waveN + ni * 16 + l15] * c16;

    float psum = 0.f;
    if (ti != tj) {
        // off-diagonal tile: no per-element diagonal check (2016/2080 blocks)
        #pragma unroll
        for (int mi = 0; mi < 4; ++mi) {
            #pragma unroll
            for (int ni = 0; ni < 4; ++ni) {
                #pragma unroll
                for (int r = 0; r < 4; ++r) {
                    float g   = (float)acc[mi][ni][r];   // exact: |G| < 2^24
                    float t16 = __builtin_fmaf(g, cgq, trow16[mi * 4 + r]) + tcol16[ni];
                    float e1  = __builtin_amdgcn_exp2f(t16);
                    float e2  = e1 * e1;
                    float e4  = e2 * e2;
                    float e8  = e4 * e4;
                    float e16 = e8 * e8;
                    psum += ((e1 + e2) + (e4 + e8)) + e16;
                }
            }
        }
    } else {
        #pragma unroll
        for (int mi = 0; mi < 4; ++mi) {
            #pragma unroll
            for (int ni = 0; ni < 4; ++ni) {
                #pragma unroll
                for (int r = 0; r < 4; ++r) {
                    float g   = (float)acc[mi][ni][r];
                    float t16 = __builtin_fmaf(g, cgq, trow16[mi * 4 + r]) + tcol16[ni];
                    float e1  = __builtin_amdgcn_exp2f(t16);
                    float e2  = e1 * e1;
                    float e4  = e2 * e2;
                    float e8  = e4 * e4;
                    float e16 = e8 * e8;
                    float ks5 = ((e1 + e2) + (e4 + e8)) + e16;
                    int rl = waveM + mi * 16 + quad * 4 + r;
                    int cl = waveN + ni * 16 + l15;
                    psum += (rl == cl) ? 5.0f : ks5;     // exact diagonal
                }
            }
        }
    }

    // block reduction: alias scratch into lds (last frag reads are behind
    // the loop's final __syncthreads, so reuse is safe)
    float* red = (float*)lds;
    __shared__ bool isLast;
    float w = waveReduce(psum);
    if (lane == 0) red[wave] = w;
    __syncthreads();
    if (tid == 0) {
        float tot   = red[0] + red[1] + red[2] + red[3];
        float sign  = ((ti < 32) == (tj < 32)) ? 1.f : -1.f;
        float scale = (ti == tj) ? sign : 2.f * sign;
        blockpart[hwbid] = tot * scale;      // unique slot, no atomic
        __threadfence();                     // release before ticket
        isLast = (atomicAdd(cnt, 1u) == NBLK_MMD - 1);
    }
    __syncthreads();
    if (!isLast) return;
    __threadfence();                         // acquire: see all blockparts

    float s = 0.f;
    for (int i = tid; i < NBLK_MMD; i += 256) s += blockpart[i];
    float ws = waveReduce(s);
    if (lane == 0) red[wave] = ws;
    __syncthreads();
    if (tid == 0)
        out[0] = (red[0] + red[1] + red[2] + red[3]) * (1.f / (4096.f * 4096.f));
}

extern "C" void kernel_launch(void* const* d_in, const int* in_sizes, int n_in,
                              void* d_out, int out_size, void* d_ws, size_t ws_size,
                              hipStream_t stream) {
    const float* src = (const float*)d_in[0];
    const float* tgt = (const float*)d_in[1];

    uint8_t* ws = (uint8_t*)d_ws;
    unsigned char* Tp = (unsigned char*)ws;                    // 4,194,304 B
    size_t off = 4194304;
    float* sq      = (float*)(ws + off); off += 32768;         // 8192 f
    int*   partial = (int*)  (ws + off); off += 128 * 512 * 4; // 256 KB
    float* bp      = (float*)(ws + off); off += 8320;
    float* c16     = (float*)(ws + off); off += 64;            // pad/align
    unsigned int* cnt = (unsigned int*)(ws + off);             // 2 tickets

    k_rowstats<<<2048, 256, 0, stream>>>(src, tgt, Tp, sq, cnt);
    k_colbw   <<<64, 256, 0, stream>>>((const unsigned int*)Tp, sq, partial, c16, cnt);
    k_mmd     <<<NBLK_MMD, 256, 0, stream>>>(Tp, sq, c16, bp, (float*)d_out, cnt + 1);
}

// Round 6
// 125.803 us; speedup vs baseline: 1.1869x; 1.1869x over previous
//
#include <hip/hip_runtime.h>
#include <cstdint>
#include <cstddef>

// MMD loss, N=8192 (b=4096), D=512.
//   bw closed form: sum(L2) = 2n*S - 2*||colsum||^2
//   R9: R8 regressed (149us): the per-block __threadfence + SINGLE-ADDRESS
//       atomic ticket serialized block retirement: +47us on k_mmd (2080
//       blocks x ~54cyc same-address RMW chain). Also: gap analysis shows
//       ~45us FIXED overhead independent of kernel count (hop theory dead);
//       only sum-of-kernel-durations is addressable. Fixes:
//       (a) k_mmd ticket -> hierarchical fence-free: agent-scope blockpart
//           store + s_waitcnt vmcnt(0) (NO buffer_wbl2) + relaxed agent
//           atomics into 64 line-spread L1 counters -> 1 L2 counter.
//           Winner reads blockparts with agent-scope loads (coherent at
//           MALL; no stale-L2 risk). Serial chain 2080 -> max(33)+64.
//       (b) k_rowstats: one block per rb (16 rows); quantize -> LDS
//           (pitch 528) -> fully-coalesced 256B-chunk frag-major writeout
//           (R8 scattered 8B stores at stride 256 = 64 transactions/wave).
//           Fuses colsum partials from LDS (k_colbw kernel deleted).
//   R8: 5->3 kernels. Kept: dtile-split epilogue; replay-safe ticket zeroing.
//   R7: LDS-staged double-buffered k_mmd (global_load_lds width=16),
//       XCD-aware block swizzle (2080 = 8*260, bijective).
//   R6: FRAGMENT-MAJOR int8 layout: chunk (rb,c) [16 rows x 16B] contiguous
//       256B; a wave's fragment load = one coalesced 1KB transaction.
//   R4: INT8 MFMA 16x16x64 (scale 1/16, exact int32 acc), diag forced exact.
//   Epilogue: sum_k exp(-L2/(bw*2^k)) = e+e^2+e^4+e^8+e^16, e=exp2(-L2*log2e/(16bw))
//   R2: no single-address atomics in the hot path.

#define D_DIM 512
#define B_ROWS 4096
#define N_ROWS 8192
#define NTILES 64        // 8192 / 128
#define NBLK_MMD 2080    // 64*65/2
#define LDS_HALF 8192    // A (or B) panel slice per K-step: 8 rb x 1KB
#define LDS_BUF 16384    // A + B per K-step
#define QPITCH 528       // rowstats LDS row pitch (512 + 16 pad)

typedef __attribute__((ext_vector_type(4))) int i32x4;

__device__ inline float waveReduce(float v) {
    #pragma unroll
    for (int off = 32; off > 0; off >>= 1) v += __shfl_down(v, off, 64);
    return v;
}

__device__ inline int q8(float x) {
    int v = (int)rintf(x * 16.f);             // RNE; s = 1/16
    v = v > 127 ? 127 : v;
    v = v < -127 ? -127 : v;
    return v & 255;
}

// Fragment-major address: row r, 16B-chunk c (0..31):
//   rb = r>>4, w = r&15;  byte addr = ((rb*32 + c) << 8) + w*16

// ---- K1: sq norms + int8 quantize (coalesced frag-major via LDS) +
//          fused per-rb column-sum partials. One block per rb (16 rows). ----
__global__ __launch_bounds__(256) void k_rowstats(const float* __restrict__ src,
                                                  const float* __restrict__ tgt,
                                                  unsigned char* __restrict__ Tp,
                                                  float* __restrict__ sq,
                                                  int* __restrict__ partial,
                                                  unsigned int* __restrict__ tk) {
    if (blockIdx.x == 0 && threadIdx.x < 65)
        tk[threadIdx.x * 16] = 0u;           // 64 L1 counters + 1 L2 (replay-safe)

    __shared__ unsigned char Q[16 * QPITCH]; // 8448 B
    int tid = threadIdx.x, wave = tid >> 6, lane = tid & 63;
    int rb = blockIdx.x;                     // 0..511

    #pragma unroll
    for (int i = 0; i < 4; ++i) {
        int rl  = wave * 4 + i;
        int row = rb * 16 + rl;
        const float* base = (row < B_ROWS) ? (src + (size_t)row * D_DIM)
                                           : (tgt + (size_t)(row - B_ROWS) * D_DIM);
        float4 a = ((const float4*)base)[lane * 2];
        float4 b = ((const float4*)base)[lane * 2 + 1];
        uint2 o;  // bytes [8*lane, 8*lane+8) of the quantized row
        o.x = (unsigned)(q8(a.x) | (q8(a.y) << 8) | (q8(a.z) << 16) | (q8(a.w) << 24));
        o.y = (unsigned)(q8(b.x) | (q8(b.y) << 8) | (q8(b.z) << 16) | (q8(b.w) << 24));
        *(uint2*)(Q + rl * QPITCH + lane * 8) = o;   // 2-way bank alias: free
        float s = a.x*a.x + a.y*a.y + a.z*a.z + a.w*a.w
                + b.x*b.x + b.y*b.y + b.z*b.z + b.w*b.w;
        s = waveReduce(s);                   // same order as before: sq bitwise identical
        if (lane == 0) sq[row] = s;
    }
    __syncthreads();

    // column-sum partials: 2 cols per thread (ushort LDS read = 2 bytes)
    int s0 = 0, s1 = 0;
    #pragma unroll
    for (int r = 0; r < 16; ++r) {
        unsigned short v = *(const unsigned short*)(Q + r * QPITCH + tid * 2);
        s0 += (int)(signed char)(v & 255);
        s1 += (int)(signed char)(v >> 8);
    }
    int2 pv; pv.x = s0; pv.y = s1;
    *(int2*)(partial + (size_t)rb * 512 + tid * 2) = pv;

    // frag-major writeout: thread t -> chunk c = t>>3, rows idx*2, idx*2+1.
    // Whole wave writes 2KB contiguous; block writes the full 8KB rb panel.
    int c = tid >> 3, idx = tid & 7;
    uint4 lo = *(const uint4*)(Q + (idx * 2)     * QPITCH + c * 16);
    uint4 hi = *(const uint4*)(Q + (idx * 2 + 1) * QPITCH + c * 16);
    unsigned char* gout = Tp + ((size_t)rb << 13) + c * 256 + idx * 32;
    *(uint4*)(gout)      = lo;
    *(uint4*)(gout + 16) = hi;
}

// ---- K2: finalize bandwidth -> c16 = -log2(e)/(16*bw) (1 block) ----
__global__ __launch_bounds__(512) void k_bw(const int* __restrict__ partial,
                                            const float* __restrict__ sq,
                                            float* __restrict__ c16out) {
    int t = threadIdx.x;
    int csum = 0;
    #pragma unroll 8
    for (int i = 0; i < 512; ++i) csum += partial[i * 512 + t];   // coalesced
    float cs = (float)csum * 0.0625f;          // * s (1/16)
    float p = cs * cs;
    float ssq = 0.f;
    #pragma unroll
    for (int i = 0; i < 16; ++i) ssq += sq[t + i * 512];
    __shared__ float r8[8], q8s[8];
    float wp = waveReduce(p);
    float wq = waveReduce(ssq);
    if ((t & 63) == 0) { r8[t >> 6] = wp; q8s[t >> 6] = wq; }
    __syncthreads();
    if (t == 0) {
        double P = 0.0, Q = 0.0;
        #pragma unroll
        for (int i = 0; i < 8; ++i) { P += r8[i]; Q += q8s[i]; }
        double n = (double)N_ROWS;
        double sumL2 = 2.0 * n * Q - 2.0 * P;
        double bw = sumL2 / (n * n - n) / 4.0;   // / KERNEL_MUL^(NUM/2)
        c16out[0] = (float)(-1.4426950408889634 / (16.0 * bw));
    }
}

// ---- K3: LDS-staged int8 Gram + fused MMD epilogue + hierarchical ticket ----
__global__ __launch_bounds__(256) void k_mmd(const unsigned char* __restrict__ Tp,
                                             const float* __restrict__ sq,
                                             const float* __restrict__ c16in,
                                             float* __restrict__ blockpart,
                                             float* __restrict__ out,
                                             unsigned int* __restrict__ tk) {
    // XCD swizzle: 2080 = 8 * 260 exactly -> bijective chunked remap.
    int hwbid = (int)blockIdx.x;
    int bid = (hwbid & 7) * 260 + (hwbid >> 3);

    int rem = bid;
    int ti = 0, rowlen = NTILES;
    while (rem >= rowlen) { rem -= rowlen; rowlen--; ti++; }
    int tj = ti + rem;

    int tid  = threadIdx.x;
    int wave = tid >> 6;
    int lane = tid & 63;
    int waveM = (wave >> 1) * 64;
    int waveN = (wave & 1) * 64;
    int l15   = lane & 15;
    int quad  = lane >> 4;

    float c16 = c16in[0];                    // -log2e/(16 bw)
    float cgq = -2.f * c16 * (1.f / 256.f);  // fold s^2 = 1/256

    int rbA0 = ti * 8;                       // panel bases (rb units)
    int rbB0 = tj * 8;

    __shared__ unsigned char lds[2 * LDS_BUF];   // 32 KB, double-buffered

    i32x4 acc[4][4];
    #pragma unroll
    for (int mi = 0; mi < 4; ++mi)
        #pragma unroll
        for (int ni = 0; ni < 4; ++ni)
            acc[mi][ni] = (i32x4){0, 0, 0, 0};

    // Stage K-step kk into buffer buf. Each wave: 4 x global_load_lds of
    // 1KB (lanes linear, 16B each). Wave w covers rb_local {2w, 2w+1} of
    // both panels. LDS layout = frag-major 1KB per rb_local, A then B.
    auto stage = [&](int buf, int kk) {
        unsigned char* lbase = lds + buf * LDS_BUF;
        #pragma unroll
        for (int s = 0; s < 2; ++s) {
            int rbl = wave * 2 + s;
            const unsigned char* gA =
                Tp + (((size_t)((rbA0 + rbl) * 32 + kk * 4)) << 8) + lane * 16;
            const unsigned char* gB =
                Tp + (((size_t)((rbB0 + rbl) * 32 + kk * 4)) << 8) + lane * 16;
            __builtin_amdgcn_global_load_lds(
                (const __attribute__((address_space(1))) void*)gA,
                (__attribute__((address_space(3))) void*)(lbase + rbl * 1024 + lane * 16),
                16, 0, 0);
            __builtin_amdgcn_global_load_lds(
                (const __attribute__((address_space(1))) void*)gB,
                (__attribute__((address_space(3))) void*)(lbase + LDS_HALF + rbl * 1024 + lane * 16),
                16, 0, 0);
        }
    };

    stage(0, 0);
    __syncthreads();                         // drains vmcnt(0) + barrier

    int aoff = ((wave >> 1) * 4) * 1024 + quad * 256 + l15 * 16;
    int boff = ((wave & 1) * 4) * 1024 + quad * 256 + l15 * 16;

    int buf = 0;
    for (int kk = 0; kk < 8; ++kk) {
        if (kk < 7) stage(buf ^ 1, kk + 1);  // prefetch next K-step

        const unsigned char* bufA = lds + buf * LDS_BUF;
        const unsigned char* bufB = bufA + LDS_HALF;
        i32x4 af[4], bf[4];
        #pragma unroll
        for (int mi = 0; mi < 4; ++mi)
            af[mi] = *(const i32x4*)(bufA + aoff + mi * 1024);
        #pragma unroll
        for (int ni = 0; ni < 4; ++ni)
            bf[ni] = *(const i32x4*)(bufB + boff + ni * 1024);
        #pragma unroll
        for (int mi = 0; mi < 4; ++mi)
            #pragma unroll
            for (int ni = 0; ni < 4; ++ni)
                acc[mi][ni] = __builtin_amdgcn_mfma_i32_16x16x64_i8(
                    af[mi], bf[ni], acc[mi][ni], 0, 0, 0);

        __syncthreads();                     // staged data ready; buf reusable
        buf ^= 1;
    }

    // epilogue: sq loads direct from global (tiny, L2-hot), pre-scaled
    const float* sqA = sq + ti * 128;
    const float* sqB = sq + tj * 128;
    float trow16[16];
    #pragma unroll
    for (int mi = 0; mi < 4; ++mi)
        #pragma unroll
        for (int r = 0; r < 4; ++r)
            trow16[mi * 4 + r] = sqA[waveM + mi * 16 + quad * 4 + r] * c16;
    float tcol16[4];
    #pragma unroll
    for (int ni = 0; ni < 4; ++ni)
        tcol16[ni] = sqB[waveN + ni * 16 + l15] * c16;

    float psum = 0.f;
    if (ti != tj) {
        // off-diagonal tile: no per-element diagonal check (2016/2080 blocks)
        #pragma unroll
        for (int mi = 0; mi < 4; ++mi) {
            #pragma unroll
            for (int ni = 0; ni < 4; ++ni) {
                #pragma unroll
                for (int r = 0; r < 4; ++r) {
                    float g   = (float)acc[mi][ni][r];   // exact: |G| < 2^24
                    float t16 = __builtin_fmaf(g, cgq, trow16[mi * 4 + r]) + tcol16[ni];
                    float e1  = __builtin_amdgcn_exp2f(t16);
                    float e2  = e1 * e1;
                    float e4  = e2 * e2;
                    float e8  = e4 * e4;
                    float e16 = e8 * e8;
                    psum += ((e1 + e2) + (e4 + e8)) + e16;
                }
            }
        }
    } else {
        #pragma unroll
        for (int mi = 0; mi < 4; ++mi) {
            #pragma unroll
            for (int ni = 0; ni < 4; ++ni) {
                #pragma unroll
                for (int r = 0; r < 4; ++r) {
                    float g   = (float)acc[mi][ni][r];
                    float t16 = __builtin_fmaf(g, cgq, trow16[mi * 4 + r]) + tcol16[ni];
                    float e1  = __builtin_amdgcn_exp2f(t16);
                    float e2  = e1 * e1;
                    float e4  = e2 * e2;
                    float e8  = e4 * e4;
                    float e16 = e8 * e8;
                    float ks5 = ((e1 + e2) + (e4 + e8)) + e16;
                    int rl = waveM + mi * 16 + quad * 4 + r;
                    int cl = waveN + ni * 16 + l15;
                    psum += (rl == cl) ? 5.0f : ks5;     // exact diagonal
                }
            }
        }
    }

    // block reduction (scratch aliased into lds; safe behind loop's last barrier)
    float* red = (float*)lds;
    __shared__ bool isLast;
    float w = waveReduce(psum);
    if (lane == 0) red[wave] = w;
    __syncthreads();
    if (tid == 0) {
        float tot   = red[0] + red[1] + red[2] + red[3];
        float sign  = ((ti < 32) == (tj < 32)) ? 1.f : -1.f;
        float scale = (ti == tj) ? sign : 2.f * sign;
        // agent-scope store: lands at the coherent point, no L2 writeback needed
        __hip_atomic_store(&blockpart[hwbid], tot * scale,
                           __ATOMIC_RELAXED, __HIP_MEMORY_SCOPE_AGENT);
        asm volatile("s_waitcnt vmcnt(0)" ::: "memory");  // order store < ticket
        // hierarchical ticket: 64 line-spread counters (chains <= 33, parallel),
        // then one level-2 counter (64 RMWs). No __threadfence anywhere.
        unsigned g = (unsigned)hwbid & 63u;
        unsigned tgt = (g < 32u) ? 33u : 32u;            // 2080 = 32*33 + 32*32
        unsigned prev = __hip_atomic_fetch_add(&tk[g * 16], 1u,
                            __ATOMIC_RELAXED, __HIP_MEMORY_SCOPE_AGENT);
        bool last = false;
        if (prev == tgt - 1u)
            last = (__hip_atomic_fetch_add(&tk[64 * 16], 1u,
                        __ATOMIC_RELAXED, __HIP_MEMORY_SCOPE_AGENT) == 63u);
        isLast = last;
    }
    __syncthreads();
    if (!isLast) return;

    // winner: all 2080 agent-scope stores completed before their ticket RMWs,
    // and all RMWs precede ours -> agent-scope loads see every blockpart.
    float s = 0.f;
    for (int i = tid; i < NBLK_MMD; i += 256)
        s += __hip_atomic_load(&blockpart[i], __ATOMIC_RELAXED,
                               __HIP_MEMORY_SCOPE_AGENT);
    float ws = waveReduce(s);
    if (lane == 0) red[wave] = ws;
    __syncthreads();
    if (tid == 0)
        out[0] = (red[0] + red[1] + red[2] + red[3]) * (1.f / (4096.f * 4096.f));
}

extern "C" void kernel_launch(void* const* d_in, const int* in_sizes, int n_in,
                              void* d_out, int out_size, void* d_ws, size_t ws_size,
                              hipStream_t stream) {
    const float* src = (const float*)d_in[0];
    const float* tgt = (const float*)d_in[1];

    uint8_t* ws = (uint8_t*)d_ws;
    unsigned char* Tp = (unsigned char*)ws;                     // 4,194,304 B
    size_t off = 4194304;
    float* sq      = (float*)(ws + off); off += 32768;          // 8192 f
    int*   partial = (int*)  (ws + off); off += 512 * 512 * 4;  // 1 MB
    float* bp      = (float*)(ws + off); off += 8320;
    float* c16     = (float*)(ws + off); off += 64;
    unsigned int* tk = (unsigned int*)(ws + off);               // 65*16 uints

    k_rowstats<<<512, 256, 0, stream>>>(src, tgt, Tp, sq, partial, tk);
    k_bw      <<<1, 512, 0, stream>>>(partial, sq, c16);
    k_mmd     <<<NBLK_MMD, 256, 0, stream>>>(Tp, sq, c16, bp, (float*)d_out, tk);
}